// Round 9
// baseline (67.921 us; speedup 1.0000x reference)
//
#include <hip/hip_runtime.h>
#include <string.h>

#define AA (-0.75f)

__device__ __forceinline__ float k1f(float x) {
    return ((AA + 2.0f) * x - (AA + 3.0f)) * x * x + 1.0f;
}
__device__ __forceinline__ float k2f(float x) {
    return ((AA * x - 5.0f * AA) * x + 8.0f * AA) * x - 4.0f * AA;
}

__device__ __forceinline__ int reflect_clip(int idx, int size) {
    int span = size - 1;
    int i = idx < 0 ? -idx : idx;
    i = i % (2 * span);
    if (i > span) i = 2 * span - i;
    return i;
}

// LDS bank swizzle: logical element a -> a ^ ((a>>5)&31). Bijective per row.
__device__ __forceinline__ int swz(int a) { return a ^ ((a >> 5) & 31); }

typedef float f32x4 __attribute__((ext_vector_type(4)));

struct alignas(16) Tap { int4 i; float4 w; };   // 32 B, i = swizzled LDS idx

// ---- x-tap table pre-kernel: 16 batches x 512 cols = 8192 entries ----
__global__ __launch_bounds__(256)
void xtap_kernel(const float* __restrict__ rate,
                 const float* __restrict__ center,
                 Tap* __restrict__ xtab)
{
    const int idx = blockIdx.x * 256 + threadIdx.x;   // 0..8191
    const int b = idx >> 9;
    const int q = idx & 511;
    const float r  = rate[b];
    const float cx = center[2 * b + 0];
    const float g = 0.00390625f * (float)q - 1.0f;
    const float G = (g - cx) / r + cx;
    const float i = (G + 1.0f) * 0.5f * 511.0f;
    const float f0 = floorf(i);
    const float tt = i - f0;
    const int   i0 = (int)f0;
    Tap t;
    t.w = make_float4(k2f(tt + 1.0f), k1f(tt), k1f(1.0f - tt), k2f(2.0f - tt));
    t.i = make_int4(swz(reflect_clip(i0 - 1, 512)), swz(reflect_clip(i0,     512)),
                    swz(reflect_clip(i0 + 1, 512)), swz(reflect_clip(i0 + 2, 512)));
    xtab[idx] = t;
}

// ---- main kernel: NO __syncthreads. Each wave owns (b, h, 2 channels):
// loads its own 2ch x 4 tap rows, combines into its private LDS slice,
// gathers phase 2 from it. Same-wave LDS write->read is in-order (per-wave
// LDS pipe + compiler lgkmcnt) -> no block barrier, no cross-wave waiting.
__global__ __launch_bounds__(256, 4)
void pds9_kernel(const float* __restrict__ x,
                 const float* __restrict__ rate,
                 const float* __restrict__ center,
                 const Tap* __restrict__ xtab,
                 float* __restrict__ out)
{
    constexpr int C = 8, H = 512, W = 512, HW = H * W;

    // XCD-chunked remap (8192 % 8 == 0 -> bijective).
    const int orig = blockIdx.x;
    const int id = (orig & 7) * 1024 + (orig >> 3);
    const int b = id >> 9;
    const int h = id & (H - 1);
    const int t    = threadIdx.x;
    const int wid  = t >> 6;          // wave 0..3
    const int lane = t & 63;
    const int ch0  = wid * 2;

    const float r  = rate[b];
    const float cy = center[2 * b + 1];
    const float inv_r = 1.0f / r;

    // ---- y taps (uniform, inline: short chain, NO load dependency) ----
    const float gy = 0.00390625f * (float)h - 1.0f;
    const float Gy = (gy - cy) * inv_r + cy;
    const float iy = (Gy + 1.0f) * 0.5f * 511.0f;
    const float y0 = floorf(iy);
    const float ty = iy - y0;
    const int   y0i = (int)y0;
    const float wy0 = k2f(ty + 1.0f);
    const float wy1 = k1f(ty);
    const float wy2 = k1f(1.0f - ty);
    const float wy3 = k2f(2.0f - ty);
    const int ro0 = reflect_clip(y0i - 1, H) * W;
    const int ro1 = reflect_clip(y0i    , H) * W;
    const int ro2 = reflect_clip(y0i + 1, H) * W;
    const int ro3 = reflect_clip(y0i + 2, H) * W;

    // ---- this wave's 16 row loads (2 ch x 4 taps x 2 half-rows) ----
    const float* img0 = x + (size_t)b * C * HW + (size_t)ch0 * HW;
    const float* img1 = img0 + HW;
    const int o0 = lane << 2;          // floats [0,256): lane*4
    const int o1 = 256 + (lane << 2);  // floats [256,512)

    f32x4 aA0 = *(const f32x4*)(img0 + ro0 + o0);
    f32x4 aA1 = *(const f32x4*)(img0 + ro1 + o0);
    f32x4 aA2 = *(const f32x4*)(img0 + ro2 + o0);
    f32x4 aA3 = *(const f32x4*)(img0 + ro3 + o0);
    f32x4 aB0 = *(const f32x4*)(img0 + ro0 + o1);
    f32x4 aB1 = *(const f32x4*)(img0 + ro1 + o1);
    f32x4 aB2 = *(const f32x4*)(img0 + ro2 + o1);
    f32x4 aB3 = *(const f32x4*)(img0 + ro3 + o1);
    f32x4 cA0 = *(const f32x4*)(img1 + ro0 + o0);
    f32x4 cA1 = *(const f32x4*)(img1 + ro1 + o0);
    f32x4 cA2 = *(const f32x4*)(img1 + ro2 + o0);
    f32x4 cA3 = *(const f32x4*)(img1 + ro3 + o0);
    f32x4 cB0 = *(const f32x4*)(img1 + ro0 + o1);
    f32x4 cB1 = *(const f32x4*)(img1 + ro1 + o1);
    f32x4 cB2 = *(const f32x4*)(img1 + ro2 + o1);
    f32x4 cB3 = *(const f32x4*)(img1 + ro3 + o1);
    __builtin_amdgcn_sched_barrier(0);

    __shared__ float tmp[C][W];   // 16 KiB; wave w touches rows ch0,ch0+1 only

    // ---- vertical combine -> swizzled LDS (this wave's rows only) ----
#define COMB1(cc, c4, a0, a1, a2, a3)                                      \
    {                                                                      \
        const int v    = ((c4) >> 5) & 31;                                 \
        const int base = (c4) ^ (v & ~3);                                  \
        const int p    = v & 3;                                            \
        const bool q1 = (p & 1) != 0;                                      \
        const bool q2 = (p & 2) != 0;                                      \
        float e0 = wy0 * a0.x + wy1 * a1.x + wy2 * a2.x + wy3 * a3.x;      \
        float e1 = wy0 * a0.y + wy1 * a1.y + wy2 * a2.y + wy3 * a3.y;      \
        float e2 = wy0 * a0.z + wy1 * a1.z + wy2 * a2.z + wy3 * a3.z;      \
        float e3 = wy0 * a0.w + wy1 * a1.w + wy2 * a2.w + wy3 * a3.w;      \
        float t0 = q1 ? e1 : e0;                                           \
        float t1 = q1 ? e0 : e1;                                           \
        float t2 = q1 ? e3 : e2;                                           \
        float t3 = q1 ? e2 : e3;                                           \
        float u0 = q2 ? t2 : t0;                                           \
        float u1 = q2 ? t3 : t1;                                           \
        float u2 = q2 ? t0 : t2;                                           \
        float u3 = q2 ? t1 : t3;                                           \
        *(float4*)&tmp[cc][base] = make_float4(u0, u1, u2, u3);            \
    }
    COMB1(ch0,     o0, aA0, aA1, aA2, aA3);
    COMB1(ch0,     o1, aB0, aB1, aB2, aB3);
    COMB1(ch0 + 1, o0, cA0, cA1, cA2, cA3);
    COMB1(ch0 + 1, o1, cB0, cB1, cB2, cB3);
#undef COMB1

    // ---- phase 2: 4 col-pair groups x 2 channels, taps from L2-hot table.
    // Taps loaded after combine (p-regs dead -> VGPR peak stays ~80).
    const Tap* xt = xtab + (b << 9);
    const float* r0 = tmp[ch0];
    const float* r1 = tmp[ch0 + 1];
    float* ob0 = out + (((size_t)b * C + ch0) * H + h) * W;
    float* ob1 = ob0 + (size_t)HW;

    #pragma unroll
    for (int k = 0; k < 4; ++k) {
        const int col = (k << 7) + (lane << 1);
        const Tap ea = xt[col];
        const Tap eb = xt[col + 1];
        const float s00 = ea.w.x * r0[ea.i.x] + ea.w.y * r0[ea.i.y]
                        + ea.w.z * r0[ea.i.z] + ea.w.w * r0[ea.i.w];
        const float s01 = eb.w.x * r0[eb.i.x] + eb.w.y * r0[eb.i.y]
                        + eb.w.z * r0[eb.i.z] + eb.w.w * r0[eb.i.w];
        const float s10 = ea.w.x * r1[ea.i.x] + ea.w.y * r1[ea.i.y]
                        + ea.w.z * r1[ea.i.z] + ea.w.w * r1[ea.i.w];
        const float s11 = eb.w.x * r1[eb.i.x] + eb.w.y * r1[eb.i.y]
                        + eb.w.z * r1[eb.i.z] + eb.w.w * r1[eb.i.w];
        float2 v0 = make_float2(s00, s01);
        float2 v1 = make_float2(s10, s11);
        double d0, d1;
        memcpy(&d0, &v0, 8);
        memcpy(&d1, &v1, 8);
        __builtin_nontemporal_store(d0, (double*)(ob0 + col));
        __builtin_nontemporal_store(d1, (double*)(ob1 + col));
    }
}

extern "C" void kernel_launch(void* const* d_in, const int* in_sizes, int n_in,
                              void* d_out, int out_size, void* d_ws, size_t ws_size,
                              hipStream_t stream) {
    const float* x      = (const float*)d_in[0];
    const float* rate   = (const float*)d_in[1];
    const float* center = (const float*)d_in[2];
    float* out          = (float*)d_out;

    constexpr int B = 16, H = 512;
    const size_t TAB = (size_t)8192 * sizeof(Tap);   // 256 KB

    Tap* xtab = (Tap*)d_ws;   // ws_size >= 256 KB (held in prior rounds)
    if (ws_size >= TAB) {
        xtap_kernel<<<32, 256, 0, stream>>>(rate, center, xtab);
        pds9_kernel<<<B * H, 256, 0, stream>>>(x, rate, center, xtab, out);
    }
}

// Round 10
// 56.663 us; speedup vs baseline: 1.1987x; 1.1987x over previous
//
#include <hip/hip_runtime.h>
#include <string.h>

#define AA (-0.75f)

__device__ __forceinline__ float k1f(float x) {
    return ((AA + 2.0f) * x - (AA + 3.0f)) * x * x + 1.0f;
}
__device__ __forceinline__ float k2f(float x) {
    return ((AA * x - 5.0f * AA) * x + 8.0f * AA) * x - 4.0f * AA;
}

__device__ __forceinline__ int reflect_clip(int idx, int size) {
    int span = size - 1;
    int i = idx < 0 ? -idx : idx;
    i = i % (2 * span);
    if (i > span) i = 2 * span - i;
    return i;
}

// LDS bank swizzle: logical element a -> a ^ ((a>>5)&31). Bijective per row.
__device__ __forceinline__ int swz(int a) { return a ^ ((a >> 5) & 31); }

typedef float f32x4 __attribute__((ext_vector_type(4)));

// Inline-asm load: cannot be sunk by IR passes (volatile), result regs forced
// live by dataflow -> guarantees a real 16-deep load burst (R5/R7/R8 showed
// the compiler otherwise serializes phase 1 into load->use pairs; VGPR=32-40
// proved the burst never existed).
#define GLOAD4(dst, ptr)                                                     \
    asm volatile("global_load_dwordx4 %0, %1, off"                           \
                 : "=v"(dst) : "v"(ptr))

// Separable bicubic, one block per (b,h), 256 threads. R5 structure with a
// forced load burst: 16x asm global_load_dwordx4 -> x-tap VALU under flight
// -> ONE asm s_waitcnt vmcnt(0) + sched_barrier(0) (rule #18) -> combine ->
// swizzled LDS -> horizontal 4-tap -> NT float2 stores.
__global__ __launch_bounds__(256, 4)
void pds10_kernel(const float* __restrict__ x,
                  const float* __restrict__ rate,
                  const float* __restrict__ center,
                  float* __restrict__ out)
{
    constexpr int C = 8, H = 512, W = 512, HW = H * W;

    // XCD-chunked remap (8192 % 8 == 0 -> bijective).
    const int orig = blockIdx.x;
    const int id = (orig & 7) * 1024 + (orig >> 3);
    const int b = id >> 9;
    const int h = id & (H - 1);

    const float r  = rate[b];
    const float cx = center[2 * b + 0];
    const float cy = center[2 * b + 1];
    const float inv_r = 1.0f / r;
    const int t = threadIdx.x;

    // ---- y taps (block-uniform, short chain) ----
    const float gy = 0.00390625f * (float)h - 1.0f;
    const float Gy = (gy - cy) * inv_r + cy;
    const float iy = (Gy + 1.0f) * 0.5f * 511.0f;
    const float y0 = floorf(iy);
    const float ty = iy - y0;
    const int   y0i = (int)y0;
    const float wy0 = k2f(ty + 1.0f);
    const float wy1 = k1f(ty);
    const float wy2 = k1f(1.0f - ty);
    const float wy3 = k2f(2.0f - ty);
    const int ro0 = reflect_clip(y0i - 1, H) * W;
    const int ro1 = reflect_clip(y0i    , H) * W;
    const int ro2 = reflect_clip(y0i + 1, H) * W;
    const int ro3 = reflect_clip(y0i + 2, H) * W;

    // ---- 16-deep load burst (asm: cannot be serialized) ----
    const float* imgb = x + (size_t)b * C * HW;
    const int cc4 = (t & 127) << 2;           // 16B-aligned group in row
    const int ch0 = (t >> 7);                 // 0 or 1
    const float* base0 = imgb + (size_t)(ch0 + 0) * HW + cc4;
    const float* base1 = imgb + (size_t)(ch0 + 2) * HW + cc4;
    const float* base2 = imgb + (size_t)(ch0 + 4) * HW + cc4;
    const float* base3 = imgb + (size_t)(ch0 + 6) * HW + cc4;

    f32x4 p00, p01, p02, p03, p10, p11, p12, p13;
    f32x4 p20, p21, p22, p23, p30, p31, p32, p33;
    GLOAD4(p00, base0 + ro0);
    GLOAD4(p01, base0 + ro1);
    GLOAD4(p02, base0 + ro2);
    GLOAD4(p03, base0 + ro3);
    GLOAD4(p10, base1 + ro0);
    GLOAD4(p11, base1 + ro1);
    GLOAD4(p12, base1 + ro2);
    GLOAD4(p13, base1 + ro3);
    GLOAD4(p20, base2 + ro0);
    GLOAD4(p21, base2 + ro1);
    GLOAD4(p22, base2 + ro2);
    GLOAD4(p23, base2 + ro3);
    GLOAD4(p30, base3 + ro0);
    GLOAD4(p31, base3 + ro1);
    GLOAD4(p32, base3 + ro2);
    GLOAD4(p33, base3 + ro3);

    // ---- x taps for cols 2t, 2t+1 (VALU under load flight; these do NOT
    // read the p-regs so they may legally schedule before the waitcnt) ----
    int   sA0, sA1, sA2, sA3, sB0, sB1, sB2, sB3;
    float wxA0, wxA1, wxA2, wxA3, wxB0, wxB1, wxB2, wxB3;
    {
        const int w = 2 * t;
        const float gx = 0.00390625f * (float)w - 1.0f;
        const float Gx = (gx - cx) * inv_r + cx;
        const float ix = (Gx + 1.0f) * 0.5f * 511.0f;
        const float x0 = floorf(ix);
        const float tx = ix - x0;
        const int x0i = (int)x0;
        wxA0 = k2f(tx + 1.0f); wxA1 = k1f(tx);
        wxA2 = k1f(1.0f - tx); wxA3 = k2f(2.0f - tx);
        sA0 = swz(reflect_clip(x0i - 1, W)); sA1 = swz(reflect_clip(x0i,     W));
        sA2 = swz(reflect_clip(x0i + 1, W)); sA3 = swz(reflect_clip(x0i + 2, W));
    }
    {
        const int w = 2 * t + 1;
        const float gx = 0.00390625f * (float)w - 1.0f;
        const float Gx = (gx - cx) * inv_r + cx;
        const float ix = (Gx + 1.0f) * 0.5f * 511.0f;
        const float x0 = floorf(ix);
        const float tx = ix - x0;
        const int x0i = (int)x0;
        wxB0 = k2f(tx + 1.0f); wxB1 = k1f(tx);
        wxB2 = k1f(1.0f - tx); wxB3 = k2f(2.0f - tx);
        sB0 = swz(reflect_clip(x0i - 1, W)); sB1 = swz(reflect_clip(x0i,     W));
        sB2 = swz(reflect_clip(x0i + 1, W)); sB3 = swz(reflect_clip(x0i + 2, W));
    }

    // ---- wait for the asm loads (compiler does NOT track them), then pin
    // all dependent VALU below (rule #18: sched_barrier after asm waitcnt) ----
    asm volatile("s_waitcnt vmcnt(0)" ::: "memory");
    __builtin_amdgcn_sched_barrier(0);

    __shared__ float tmp[C][W];   // 16 KiB, swizzled rows

    // ---- vertical combine -> swizzled LDS ----
    {
        const int v    = (cc4 >> 5) & 31;
        const int base = cc4 ^ (v & ~3);
        const int p    = v & 3;
        const bool q1 = (p & 1) != 0;
        const bool q2 = (p & 2) != 0;
#define COMB1(cc, a0, a1, a2, a3)                                          \
        {                                                                  \
            float e0 = wy0 * a0.x + wy1 * a1.x + wy2 * a2.x + wy3 * a3.x;  \
            float e1 = wy0 * a0.y + wy1 * a1.y + wy2 * a2.y + wy3 * a3.y;  \
            float e2 = wy0 * a0.z + wy1 * a1.z + wy2 * a2.z + wy3 * a3.z;  \
            float e3 = wy0 * a0.w + wy1 * a1.w + wy2 * a2.w + wy3 * a3.w;  \
            float t0 = q1 ? e1 : e0;                                       \
            float t1 = q1 ? e0 : e1;                                       \
            float t2 = q1 ? e3 : e2;                                       \
            float t3 = q1 ? e2 : e3;                                       \
            float u0 = q2 ? t2 : t0;                                       \
            float u1 = q2 ? t3 : t1;                                       \
            float u2 = q2 ? t0 : t2;                                       \
            float u3 = q2 ? t1 : t3;                                       \
            *(float4*)&tmp[cc][base] = make_float4(u0, u1, u2, u3);        \
        }
        COMB1(ch0 + 0, p00, p01, p02, p03);
        COMB1(ch0 + 2, p10, p11, p12, p13);
        COMB1(ch0 + 4, p20, p21, p22, p23);
        COMB1(ch0 + 6, p30, p31, p32, p33);
#undef COMB1
    }
    __syncthreads();

    // ---- horizontal pass: 4 LDS taps per output, NT float2 stores ----
    float* obase = out + ((size_t)b * C * H + h) * W + 2 * t;
    #pragma unroll
    for (int c = 0; c < C; ++c) {
        const float* tr = tmp[c];
        const float s0 = wxA0 * tr[sA0] + wxA1 * tr[sA1]
                       + wxA2 * tr[sA2] + wxA3 * tr[sA3];
        const float s1 = wxB0 * tr[sB0] + wxB1 * tr[sB1]
                       + wxB2 * tr[sB2] + wxB3 * tr[sB3];
        float2 v2 = make_float2(s0, s1);
        double dv;
        memcpy(&dv, &v2, 8);
        __builtin_nontemporal_store(dv, (double*)(obase + (size_t)c * HW));
    }
}

extern "C" void kernel_launch(void* const* d_in, const int* in_sizes, int n_in,
                              void* d_out, int out_size, void* d_ws, size_t ws_size,
                              hipStream_t stream) {
    const float* x      = (const float*)d_in[0];
    const float* rate   = (const float*)d_in[1];
    const float* center = (const float*)d_in[2];
    float* out          = (float*)d_out;

    constexpr int B = 16, H = 512;
    dim3 grid(B * H);
    dim3 block(256);
    pds10_kernel<<<grid, block, 0, stream>>>(x, rate, center, out);
}